// Round 6
// baseline (436.882 us; speedup 1.0000x reference)
//
#include <hip/hip_runtime.h>
#include <math.h>

#define NQ    6
#define QDIM  64
#define BB    128
#define CC    64
#define TT    2048
#define DD    256
#define NCH   128
#define CHLEN 16
#define HH    128
#define NCP   60

typedef __bf16 bf16x8 __attribute__((ext_vector_type(8)));
typedef float  f32x4  __attribute__((ext_vector_type(4)));

__device__ __forceinline__ float fast_tanh(float x) {
  float e = __expf(2.f * x);
  return 1.f - 2.f / (e + 1.f);
}

__device__ __forceinline__ float wave_sum(float v) {
#pragma unroll
  for (int off = 32; off >= 1; off >>= 1) v += __shfl_xor(v, off, 64);
  return v;
}

// ---- quantum gates: one statevector per wave, (re,im) per lane ----
__device__ __forceinline__ void g_rx(float& re, float& im, int lane, int m, float half) {
  float c = __cosf(half), s = __sinf(half);
  float pre = __shfl_xor(re, m, 64);
  float pim = __shfl_xor(im, m, 64);
  float nre = c * re + s * pim;
  float nim = c * im - s * pre;
  re = nre; im = nim;
}
__device__ __forceinline__ void g_ry(float& re, float& im, int lane, int m, float half) {
  float c = __cosf(half), s = __sinf(half);
  float pre = __shfl_xor(re, m, 64);
  float pim = __shfl_xor(im, m, 64);
  float sg = (lane & m) ? s : -s;
  re = c * re + sg * pre;
  im = c * im + sg * pim;
}
__device__ __forceinline__ void g_rz(float& re, float& im, int lane, int m, float half) {
  float c = __cosf(half), s = __sinf(half);
  float sg = (lane & m) ? s : -s;
  float nre = c * re - sg * im;
  float nim = c * im + sg * re;
  re = nre; im = nim;
}
__device__ __forceinline__ void g_crx(float& re, float& im, int lane, int mc, int mt, float half) {
  float c = __cosf(half), s = __sinf(half);
  float pre = __shfl_xor(re, mt, 64);
  float pim = __shfl_xor(im, mt, 64);
  if (lane & mc) {
    float nre = c * re + s * pim;
    float nim = c * im - s * pre;
    re = nre; im = nim;
  }
}
__device__ __forceinline__ void ansatz_layer(float& re, float& im, int lane,
                                             const float* p) {
#pragma unroll
  for (int q = 0; q < 6; ++q) {
    int m = 1 << (5 - q);
    g_rx(re, im, lane, m, 0.5f * p[3 * q + 0]);
    g_ry(re, im, lane, m, 0.5f * p[3 * q + 1]);
    g_rz(re, im, lane, m, 0.5f * p[3 * q + 2]);
  }
#pragma unroll
  for (int q = 0; q < 6; ++q)
    g_crx(re, im, lane, 1 << (5 - q), 1 << (5 - ((q + 1) % 6)), 0.5f * p[18 + q]);
#pragma unroll
  for (int q = 5; q >= 0; --q)
    g_crx(re, im, lane, 1 << (5 - q), 1 << (5 - ((q + 5) % 6)), 0.5f * p[24 + (5 - q)]);
}

// ============ K0: one-time weight prep: split-bf16 + transpose ============
__global__ __launch_bounds__(256) void k0_prep(
    const float* __restrict__ emb_w, const float* __restrict__ att_w1,
    const float* __restrict__ proj_w,
    __bf16* __restrict__ embH, __bf16* __restrict__ embL,
    __bf16* __restrict__ attH, __bf16* __restrict__ attL,
    __bf16* __restrict__ projTH, __bf16* __restrict__ projTL) {
  int idx = blockIdx.x * 256 + threadIdx.x;
  if (idx < 16384) {                       // emb: 256d x 64k
    int d = idx >> 6, k = idx & 63;
    float v = emb_w[k * 256 + d];
    __bf16 h = (__bf16)v;
    embH[idx] = h; embL[idx] = (__bf16)(v - (float)h);
  } else if (idx < 49152) {                // att: 128j x 256d
    int i = idx - 16384;
    int j = i >> 8, d = i & 255;
    float v = att_w1[d * 128 + j];
    __bf16 h = (__bf16)v;
    attH[i] = h; attL[i] = (__bf16)(v - (float)h);
  } else {                                 // projT: 64n x 256d (rows>=60 zero)
    int i = idx - 49152;
    int n = i >> 8, d = i & 255;
    float v = (n < 60) ? proj_w[d * 60 + n] : 0.f;
    __bf16 h = (__bf16)v;
    projTH[i] = h; projTL[i] = (__bf16)(v - (float)h);
  }
}

// ============ K1: fully fused embed+attn+softmax+agg+proj+ansatz ============
// Split-bf16 3-product MFMA. m89 layouts: A[m=lane&15][k=quad*8+j],
// B[n=lane&15][k=quad*8+j], C: n=lane&15, m=quad*4+reg.
// feats streamed through a 2-slice LDS double buffer (4 d-segs of 64):
// GEMM1 produces slice, GEMM2 consumes it as its K-slice. Chunk agg uses the
// bilinear identity chunk = (softmax(w)@x) @ emb_w + emb_b, so feats is never
// materialized. LDS ~21 KB -> 7 blocks/CU. Ansatz fused at tail (waves 0,1).
__global__ __launch_bounds__(256) void k1_fused(
    const float* __restrict__ x, const float* __restrict__ emb_w,
    const float* __restrict__ emb_b, const float* __restrict__ att_b1,
    const float* __restrict__ att_w2, const float* __restrict__ proj_b,
    const __bf16* __restrict__ embH, const __bf16* __restrict__ embL,
    const __bf16* __restrict__ attH, const __bf16* __restrict__ attL,
    const __bf16* __restrict__ projTH, const __bf16* __restrict__ projTL,
    float2* __restrict__ evolved) {
  const int blk = blockIdx.x;            // 8192 = 128 b x 64 chunk-pairs
  const int b = blk >> 6, cp = blk & 63;
  const int tid = threadIdx.x, wv = tid >> 6, lane = tid & 63;
  const int l15 = lane & 15, quad = lane >> 4;

  __shared__ __bf16 bufH[2][32][68];     // feats slice hi (word-stride 34: 2-way free)
  __shared__ __bf16 bufL[2][32][68];
  __shared__ float  scoreS[4][32];
  __shared__ float  wSm[2][16];
  __shared__ float  xaggS[2][64];
  __shared__ float  chunkS[2][256];
  __shared__ float  paramsS[2][60];

  // ---- A fragments for GEMM1, direct from global x; held for xagg reuse ----
  bf16x8 ah[2][2], al[2][2];             // [mt][s]
  {
    const float* xb = x + (size_t)b * 64 * 2048 + cp * 32 + l15;
#pragma unroll
    for (int mt = 0; mt < 2; ++mt)
#pragma unroll
      for (int s = 0; s < 2; ++s)
#pragma unroll
        for (int j = 0; j < 8; ++j) {
          float v = xb[(size_t)(32 * s + 8 * quad + j) * 2048 + mt * 16];
          __bf16 h = (__bf16)v;
          ah[mt][s][j] = h;
          al[mt][s][j] = (__bf16)(v - (float)h);
        }
  }

  // ---- pipelined GEMM1 -> GEMM2 over 4 d-segments of 64 ----
  f32x4 acc2[2][2];                      // [mt][jt] GEMM2 accumulators
#pragma unroll
  for (int mt = 0; mt < 2; ++mt)
#pragma unroll
    for (int jt = 0; jt < 2; ++jt) acc2[mt][jt] = (f32x4){0.f, 0.f, 0.f, 0.f};

#pragma unroll
  for (int seg = 0; seg < 4; ++seg) {
    const int p = seg & 1;
    {  // GEMM1: this wave computes cols [seg*64 + wv*16, +16) for all 32 rows
      const int dg = seg * 64 + wv * 16 + l15;
      const size_t row = (size_t)dg * 64 + 8 * quad;
      bf16x8 bh0 = *(const bf16x8*)(embH + row);
      bf16x8 bl0 = *(const bf16x8*)(embL + row);
      bf16x8 bh1 = *(const bf16x8*)(embH + row + 32);
      bf16x8 bl1 = *(const bf16x8*)(embL + row + 32);
      float bias = emb_b[dg];
      f32x4 a0 = (f32x4){0.f, 0.f, 0.f, 0.f}, a1 = a0;
      a0 = __builtin_amdgcn_mfma_f32_16x16x32_bf16(ah[0][0], bh0, a0, 0, 0, 0);
      a0 = __builtin_amdgcn_mfma_f32_16x16x32_bf16(al[0][0], bh0, a0, 0, 0, 0);
      a0 = __builtin_amdgcn_mfma_f32_16x16x32_bf16(ah[0][0], bl0, a0, 0, 0, 0);
      a0 = __builtin_amdgcn_mfma_f32_16x16x32_bf16(ah[0][1], bh1, a0, 0, 0, 0);
      a0 = __builtin_amdgcn_mfma_f32_16x16x32_bf16(al[0][1], bh1, a0, 0, 0, 0);
      a0 = __builtin_amdgcn_mfma_f32_16x16x32_bf16(ah[0][1], bl1, a0, 0, 0, 0);
      a1 = __builtin_amdgcn_mfma_f32_16x16x32_bf16(ah[1][0], bh0, a1, 0, 0, 0);
      a1 = __builtin_amdgcn_mfma_f32_16x16x32_bf16(al[1][0], bh0, a1, 0, 0, 0);
      a1 = __builtin_amdgcn_mfma_f32_16x16x32_bf16(ah[1][0], bl0, a1, 0, 0, 0);
      a1 = __builtin_amdgcn_mfma_f32_16x16x32_bf16(ah[1][1], bh1, a1, 0, 0, 0);
      a1 = __builtin_amdgcn_mfma_f32_16x16x32_bf16(al[1][1], bh1, a1, 0, 0, 0);
      a1 = __builtin_amdgcn_mfma_f32_16x16x32_bf16(ah[1][1], bl1, a1, 0, 0, 0);
      const int col = wv * 16 + l15;
#pragma unroll
      for (int r = 0; r < 4; ++r) {
        float v0 = a0[r] + bias;
        __bf16 h0 = (__bf16)v0;
        bufH[p][quad * 4 + r][col] = h0;
        bufL[p][quad * 4 + r][col] = (__bf16)(v0 - (float)h0);
        float v1 = a1[r] + bias;
        __bf16 h1 = (__bf16)v1;
        bufH[p][16 + quad * 4 + r][col] = h1;
        bufL[p][16 + quad * 4 + r][col] = (__bf16)(v1 - (float)h1);
      }
    }
    __syncthreads();
    // GEMM2 partial: K-slice [seg*64, +64) as 2 k-steps of 32
#pragma unroll
    for (int ss = 0; ss < 2; ++ss) {
      bf16x8 fa[2], fb[2];
#pragma unroll
      for (int mt = 0; mt < 2; ++mt) {
        fa[mt] = *(const bf16x8*)&bufH[p][mt * 16 + l15][32 * ss + 8 * quad];
        fb[mt] = *(const bf16x8*)&bufL[p][mt * 16 + l15][32 * ss + 8 * quad];
      }
#pragma unroll
      for (int jt = 0; jt < 2; ++jt) {
        const size_t row = (size_t)(wv * 32 + jt * 16 + l15) * 256 + seg * 64 + 32 * ss + 8 * quad;
        bf16x8 bh = *(const bf16x8*)(attH + row);
        bf16x8 bl = *(const bf16x8*)(attL + row);
#pragma unroll
        for (int mt = 0; mt < 2; ++mt) {
          acc2[mt][jt] = __builtin_amdgcn_mfma_f32_16x16x32_bf16(fa[mt], bh, acc2[mt][jt], 0, 0, 0);
          acc2[mt][jt] = __builtin_amdgcn_mfma_f32_16x16x32_bf16(fb[mt], bh, acc2[mt][jt], 0, 0, 0);
          acc2[mt][jt] = __builtin_amdgcn_mfma_f32_16x16x32_bf16(fa[mt], bl, acc2[mt][jt], 0, 0, 0);
        }
      }
    }
    // no 2nd barrier: next seg writes the other buffer; its barrier protects reads
  }

  {  // scores epilogue: tanh, * w2, reduce over the 16 j's in l15
    float w2v[2], b1v[2];
#pragma unroll
    for (int jt = 0; jt < 2; ++jt) {
      int j = wv * 32 + jt * 16 + l15;
      w2v[jt] = att_w2[j];
      b1v[jt] = att_b1[j];
    }
#pragma unroll
    for (int mt = 0; mt < 2; ++mt)
#pragma unroll
      for (int r = 0; r < 4; ++r) {
        float sc = fast_tanh(acc2[mt][0][r] + b1v[0]) * w2v[0] +
                   fast_tanh(acc2[mt][1][r] + b1v[1]) * w2v[1];
        sc += __shfl_xor(sc, 1, 64);
        sc += __shfl_xor(sc, 2, 64);
        sc += __shfl_xor(sc, 4, 64);
        sc += __shfl_xor(sc, 8, 64);
        if (l15 == 0) scoreS[wv][mt * 16 + quad * 4 + r] = sc;
      }
  }
  __syncthreads();

  if (tid < 2) {  // softmax over 16 per chunk (att_b2 dropped: shift-invariant)
    float s[16], mx = -1e30f;
#pragma unroll
    for (int t = 0; t < 16; ++t) {
      int tt = tid * 16 + t;
      s[t] = (scoreS[0][tt] + scoreS[1][tt]) + (scoreS[2][tt] + scoreS[3][tt]);
      mx = fmaxf(mx, s[t]);
    }
    float sum = 0.f;
#pragma unroll
    for (int t = 0; t < 16; ++t) { s[t] = __expf(s[t] - mx); sum += s[t]; }
    float inv = 1.f / sum;
#pragma unroll
    for (int t = 0; t < 16; ++t) wSm[tid][t] = s[t] * inv;
  }
  __syncthreads();

  {  // xagg[c][k] = sum_t w[c,t] * x[k][t]: shuffle-reduce the held A frags.
     // wave wv handles (mt = wv>>1, s = wv&1); hi+lo reconstruct (~2^-16 err)
    const int mt = wv >> 1, s = wv & 1;
    float wt = wSm[mt][l15];
    float vj[8];
#pragma unroll
    for (int j = 0; j < 8; ++j)
      vj[j] = wt * ((float)ah[mt][s][j] + (float)al[mt][s][j]);
#pragma unroll
    for (int off = 1; off <= 8; off <<= 1)
#pragma unroll
      for (int j = 0; j < 8; ++j) vj[j] += __shfl_xor(vj[j], off, 64);
    if (l15 == 0) {
#pragma unroll
      for (int j = 0; j < 8; ++j) xaggS[mt][32 * s + 8 * quad + j] = vj[j];
    }
  }
  __syncthreads();

  {  // chunk[c][d] = sum_k xagg[c][k]*emb_w[k][d] + emb_b[d]  (pure fp32)
    const int d = tid;
    float c0 = emb_b[d], c1 = c0;
#pragma unroll 8
    for (int k = 0; k < 64; ++k) {
      float wgt = emb_w[k * 256 + d];
      c0 = fmaf(xaggS[0][k], wgt, c0);
      c1 = fmaf(xaggS[1][k], wgt, c1);
    }
    chunkS[0][d] = c0; chunkS[1][d] = c1;
  }
  __syncthreads();

  {  // proj via MFMA: params[2][60] = sigmoid(chunk @ proj_w + b)
    const int jout = wv * 16 + l15;
    f32x4 acc3 = (f32x4){0.f, 0.f, 0.f, 0.f};
#pragma unroll
    for (int s = 0; s < 8; ++s) {
      const size_t row = (size_t)jout * 256 + 32 * s + 8 * quad;
      bf16x8 bh = *(const bf16x8*)(projTH + row);
      bf16x8 bl = *(const bf16x8*)(projTL + row);
      bf16x8 ax = (bf16x8)(__bf16)0.f, alx = (bf16x8)(__bf16)0.f;
      if (l15 < 2) {
        const float* cs = &chunkS[l15][32 * s + 8 * quad];
        float4 u0 = *(const float4*)cs, u1 = *(const float4*)(cs + 4);
        float vals[8] = {u0.x, u0.y, u0.z, u0.w, u1.x, u1.y, u1.z, u1.w};
#pragma unroll
        for (int j = 0; j < 8; ++j) {
          __bf16 h = (__bf16)vals[j];
          ax[j] = h;
          alx[j] = (__bf16)(vals[j] - (float)h);
        }
      }
      acc3 = __builtin_amdgcn_mfma_f32_16x16x32_bf16(ax, bh, acc3, 0, 0, 0);
      acc3 = __builtin_amdgcn_mfma_f32_16x16x32_bf16(alx, bh, acc3, 0, 0, 0);
      acc3 = __builtin_amdgcn_mfma_f32_16x16x32_bf16(ax, bl, acc3, 0, 0, 0);
    }
    if (jout < 60 && quad == 0) {
      float pbias = proj_b[jout];
#pragma unroll
      for (int r = 0; r < 2; ++r) {
        float a = acc3[r] + pbias;
        paramsS[r][jout] = 1.f / (1.f + __expf(-a));
      }
    }
  }
  __syncthreads();

  // ---- fused K2: waves 0,1 evolve their chunk's statevector ----
  if (wv < 2) {
    float re = (lane == 0) ? 1.f : 0.f, im = 0.f;
    const float* p = paramsS[wv];
    ansatz_layer(re, im, lane, p);
    ansatz_layer(re, im, lane, p + 30);
    evolved[((size_t)b * NCH + cp * 2 + wv) * QDIM + lane] = make_float2(re, im);
  }
}

// ============ K3: LCU mix + qff ansatz + expvals + head (512 thr) ============
__global__ __launch_bounds__(512) void k3_head(
    const float2* __restrict__ evolved, const float* __restrict__ mix_re,
    const float* __restrict__ mix_im, const float* __restrict__ qff,
    const float* __restrict__ out_w, const float* __restrict__ out_b,
    const float* __restrict__ ln_g, const float* __restrict__ ln_b,
    const float* __restrict__ cls_w1, const float* __restrict__ cls_b1,
    const float* __restrict__ cls_w2, const float* __restrict__ cls_b2,
    float* __restrict__ outp) {
  const int b = blockIdx.x, tid = threadIdx.x, wv = tid >> 6, lane = tid & 63;
  __shared__ float mreS[8][64], mimS[8][64];
  __shared__ float qfeatS[18];
  __shared__ float outS[DD];
  __shared__ float redS[8];
  __shared__ float clsR[2][DD];

  float are = 0.f, aim = 0.f;
#pragma unroll 4
  for (int t = wv * 16; t < wv * 16 + 16; ++t) {
    float2 e = evolved[((size_t)b * NCH + t) * QDIM + lane];
    float cr = mix_re[t], ci = mix_im[t];
    are = fmaf(cr, e.x, are); are = fmaf(-ci, e.y, are);
    aim = fmaf(cr, e.y, aim); aim = fmaf(ci, e.x, aim);
  }
  mreS[wv][lane] = are; mimS[wv][lane] = aim;
  __syncthreads();

  if (wv == 0) {
    float r0 = mix_re[lane], i0 = mix_im[lane];
    float r1 = mix_re[lane + 64], i1 = mix_im[lane + 64];
    float sp = sqrtf(r0 * r0 + i0 * i0) + sqrtf(r1 * r1 + i1 * i1);
    float S = wave_sum(sp) + 1e-8f;
    float re = 0.f, im = 0.f;
#pragma unroll
    for (int w = 0; w < 8; ++w) { re += mreS[w][lane]; im += mimS[w][lane]; }
    float invS = 1.f / S;
    re *= invS; im *= invS;
    float n2 = wave_sum(re * re + im * im);
    float scl = 1.f / (sqrtf(n2) + 1e-9f);
    re *= scl; im *= scl;
    float qp[30];
#pragma unroll
    for (int i = 0; i < 30; ++i) qp[i] = qff[i];
    ansatz_layer(re, im, lane, qp);
#pragma unroll
    for (int q = 0; q < 6; ++q) {
      int m = 1 << (5 - q);
      float pre = __shfl_xor(re, m, 64), pim = __shfl_xor(im, m, 64);
      float vx = re * pre + im * pim;
      float vy = (lane & m) ? (im * pre - re * pim) : (re * pim - im * pre);
      float vz = (lane & m) ? -(re * re + im * im) : (re * re + im * im);
      vx = wave_sum(vx); vy = wave_sum(vy); vz = wave_sum(vz);
      if (lane == 0) { qfeatS[q] = vx; qfeatS[6 + q] = vy; qfeatS[12 + q] = vz; }
    }
  }
  __syncthreads();

  float o = 0.f, dv = 0.f;
  if (tid < 256) {
    o = out_b[tid];
#pragma unroll
    for (int k = 0; k < 18; ++k) o = fmaf(qfeatS[k], out_w[k * DD + tid], o);
    float s1 = wave_sum(o);
    if (lane == 0) redS[wv] = s1;
  }
  __syncthreads();
  float mu = (redS[0] + redS[1] + redS[2] + redS[3]) * (1.f / 256.f);
  if (tid < 256) {
    dv = o - mu;
    float s2 = wave_sum(dv * dv);
    if (lane == 0) redS[wv] = s2;
  }
  __syncthreads();
  float var = (redS[0] + redS[1] + redS[2] + redS[3]) * (1.f / 256.f);
  if (tid < 256) {
    outS[tid] = dv / sqrtf(var + 1e-5f) * ln_g[tid] + ln_b[tid];
  }
  __syncthreads();

  {
    const int dd = tid & 255, hh = tid >> 8;
    float r = (hh == 0) ? cls_b1[dd] : 0.f;
#pragma unroll 8
    for (int d = hh * 128; d < hh * 128 + 128; ++d)
      r = fmaf(outS[d], cls_w1[(size_t)d * DD + dd], r);
    clsR[hh][dd] = r;
  }
  __syncthreads();
  if (tid < 256) {
    float r = fmaxf(clsR[0][tid] + clsR[1][tid], 0.f);
    float p0 = wave_sum(r * cls_w2[tid * 2 + 0]);
    float p1 = wave_sum(r * cls_w2[tid * 2 + 1]);
    if (lane == 0) { mreS[0][wv] = p0; mreS[1][wv] = p1; }
  }
  __syncthreads();
  if (tid == 0) {
    outp[b * 2 + 0] = (mreS[0][0] + mreS[0][1]) + (mreS[0][2] + mreS[0][3]) + cls_b2[0];
    outp[b * 2 + 1] = (mreS[1][0] + mreS[1][1]) + (mreS[1][2] + mreS[1][3]) + cls_b2[1];
  }
}

extern "C" void kernel_launch(void* const* d_in, const int* in_sizes, int n_in,
                              void* d_out, int out_size, void* d_ws, size_t ws_size,
                              hipStream_t stream) {
  const float* x      = (const float*)d_in[0];
  const float* emb_w  = (const float*)d_in[1];
  const float* emb_b  = (const float*)d_in[2];
  const float* att_w1 = (const float*)d_in[3];
  const float* att_b1 = (const float*)d_in[4];
  const float* att_w2 = (const float*)d_in[5];
  // d_in[6] att_b2: unused (softmax shift-invariant)
  const float* proj_w = (const float*)d_in[7];
  const float* proj_b = (const float*)d_in[8];
  const float* mix_re = (const float*)d_in[9];
  const float* mix_im = (const float*)d_in[10];
  const float* qff    = (const float*)d_in[11];
  const float* out_w  = (const float*)d_in[12];
  const float* out_b  = (const float*)d_in[13];
  const float* ln_g   = (const float*)d_in[14];
  const float* ln_b   = (const float*)d_in[15];
  const float* cls_w1 = (const float*)d_in[16];
  const float* cls_b1 = (const float*)d_in[17];
  const float* cls_w2 = (const float*)d_in[18];
  const float* cls_b2 = (const float*)d_in[19];

  char* ws = (char*)d_ws;
  float2* evolved = (float2*)ws;                     // 16384*64*8 = 8,388,608
  size_t off = 8388608;
  __bf16* embH   = (__bf16*)(ws + off); off += 32768;
  __bf16* embL   = (__bf16*)(ws + off); off += 32768;
  __bf16* attH   = (__bf16*)(ws + off); off += 65536;
  __bf16* attL   = (__bf16*)(ws + off); off += 65536;
  __bf16* projTH = (__bf16*)(ws + off); off += 32768;
  __bf16* projTL = (__bf16*)(ws + off); off += 32768;

  k0_prep<<<256, 256, 0, stream>>>(emb_w, att_w1, proj_w,
                                   embH, embL, attH, attL, projTH, projTL);
  k1_fused<<<BB * 64, 256, 0, stream>>>(
      x, emb_w, emb_b, att_b1, att_w2, proj_b,
      embH, embL, attH, attL, projTH, projTL, evolved);
  k3_head<<<BB, 512, 0, stream>>>(evolved, mix_re, mix_im, qff, out_w, out_b,
                                  ln_g, ln_b, cls_w1, cls_b1, cls_w2, cls_b2,
                                  (float*)d_out);
}

// Round 7
// 392.613 us; speedup vs baseline: 1.1128x; 1.1128x over previous
//
#include <hip/hip_runtime.h>
#include <math.h>

#define NQ    6
#define QDIM  64
#define BB    128
#define CC    64
#define TT    2048
#define DD    256
#define NCH   128
#define CHLEN 16
#define HH    128
#define NCP   60

typedef __bf16 bf16x8 __attribute__((ext_vector_type(8)));
typedef float  f32x4  __attribute__((ext_vector_type(4)));

__device__ __forceinline__ float fast_tanh(float x) {
  float e = __expf(2.f * x);
  return 1.f - 2.f / (e + 1.f);
}

__device__ __forceinline__ float wave_sum(float v) {
#pragma unroll
  for (int off = 32; off >= 1; off >>= 1) v += __shfl_xor(v, off, 64);
  return v;
}

// ---- quantum gates: one statevector per wave, (re,im) per lane ----
__device__ __forceinline__ void g_rx(float& re, float& im, int lane, int m, float half) {
  float c = __cosf(half), s = __sinf(half);
  float pre = __shfl_xor(re, m, 64);
  float pim = __shfl_xor(im, m, 64);
  float nre = c * re + s * pim;
  float nim = c * im - s * pre;
  re = nre; im = nim;
}
__device__ __forceinline__ void g_ry(float& re, float& im, int lane, int m, float half) {
  float c = __cosf(half), s = __sinf(half);
  float pre = __shfl_xor(re, m, 64);
  float pim = __shfl_xor(im, m, 64);
  float sg = (lane & m) ? s : -s;
  re = c * re + sg * pre;
  im = c * im + sg * pim;
}
__device__ __forceinline__ void g_rz(float& re, float& im, int lane, int m, float half) {
  float c = __cosf(half), s = __sinf(half);
  float sg = (lane & m) ? s : -s;
  float nre = c * re - sg * im;
  float nim = c * im + sg * re;
  re = nre; im = nim;
}
__device__ __forceinline__ void g_crx(float& re, float& im, int lane, int mc, int mt, float half) {
  float c = __cosf(half), s = __sinf(half);
  float pre = __shfl_xor(re, mt, 64);
  float pim = __shfl_xor(im, mt, 64);
  if (lane & mc) {
    float nre = c * re + s * pim;
    float nim = c * im - s * pre;
    re = nre; im = nim;
  }
}
__device__ __forceinline__ void ansatz_layer(float& re, float& im, int lane,
                                             const float* p) {
#pragma unroll
  for (int q = 0; q < 6; ++q) {
    int m = 1 << (5 - q);
    g_rx(re, im, lane, m, 0.5f * p[3 * q + 0]);
    g_ry(re, im, lane, m, 0.5f * p[3 * q + 1]);
    g_rz(re, im, lane, m, 0.5f * p[3 * q + 2]);
  }
#pragma unroll
  for (int q = 0; q < 6; ++q)
    g_crx(re, im, lane, 1 << (5 - q), 1 << (5 - ((q + 1) % 6)), 0.5f * p[18 + q]);
#pragma unroll
  for (int q = 5; q >= 0; --q)
    g_crx(re, im, lane, 1 << (5 - q), 1 << (5 - ((q + 5) % 6)), 0.5f * p[24 + (5 - q)]);
}

// ============ K0: one-time weight prep: split-bf16 + transpose ============
__global__ __launch_bounds__(256) void k0_prep(
    const float* __restrict__ emb_w, const float* __restrict__ att_w1,
    const float* __restrict__ proj_w,
    __bf16* __restrict__ embH, __bf16* __restrict__ embL,
    __bf16* __restrict__ attH, __bf16* __restrict__ attL,
    __bf16* __restrict__ projTH, __bf16* __restrict__ projTL) {
  int idx = blockIdx.x * 256 + threadIdx.x;
  if (idx < 16384) {                       // emb: 256d x 64k
    int d = idx >> 6, k = idx & 63;
    float v = emb_w[k * 256 + d];
    __bf16 h = (__bf16)v;
    embH[idx] = h; embL[idx] = (__bf16)(v - (float)h);
  } else if (idx < 49152) {                // att: 128j x 256d
    int i = idx - 16384;
    int j = i >> 8, d = i & 255;
    float v = att_w1[d * 128 + j];
    __bf16 h = (__bf16)v;
    attH[i] = h; attL[i] = (__bf16)(v - (float)h);
  } else {                                 // projT: 64n x 256d (rows>=60 zero)
    int i = idx - 49152;
    int n = i >> 8, d = i & 255;
    float v = (n < 60) ? proj_w[d * 60 + n] : 0.f;
    __bf16 h = (__bf16)v;
    projTH[i] = h; projTL[i] = (__bf16)(v - (float)h);
  }
}

// ============ K1: fully fused embed+attn+softmax+agg+proj+ansatz ============
// Split-bf16 3-product MFMA. m89 layouts: A[m=lane&15][k=quad*8+j],
// B[n=lane&15][k=quad*8+j], C: n=lane&15, m=quad*4+reg.
// x staged in LDS as split-bf16 (xH/xL) -> A-frags re-read per segment via
// ds_read_b128; NOTHING big is register-held across barriers (R6 spill fix).
// feats streamed through a 2-slice LDS double buffer (4 d-segs of 64);
// chunk agg uses bilinearity: chunk = (softmax(w)@x) @ emb_w + emb_b.
// LDS ~29 KB -> 5 blocks/CU; (256,4) caps VGPR at 128 (R5-proven, no spill).
__global__ __launch_bounds__(256, 4) void k1_fused(
    const float* __restrict__ x, const float* __restrict__ emb_w,
    const float* __restrict__ emb_b, const float* __restrict__ att_b1,
    const float* __restrict__ att_w2, const float* __restrict__ proj_b,
    const __bf16* __restrict__ embH, const __bf16* __restrict__ embL,
    const __bf16* __restrict__ attH, const __bf16* __restrict__ attL,
    const __bf16* __restrict__ projTH, const __bf16* __restrict__ projTL,
    float2* __restrict__ evolved) {
  const int blk = blockIdx.x;            // 8192 = 128 b x 64 chunk-pairs
  const int b = blk >> 6, cp = blk & 63;
  const int tid = threadIdx.x, wv = tid >> 6, lane = tid & 63;
  const int l15 = lane & 15, quad = lane >> 4;

  __shared__ __bf16 xH[32][68], xL[32][68];       // x^T split (word-stride 34)
  __shared__ __bf16 bufH[2][32][68];              // feats slice hi
  __shared__ __bf16 bufL[2][32][68];
  __shared__ float  scoreS[4][32];
  __shared__ float  wSm[2][16];
  __shared__ float  xaggS[2][64];
  __shared__ float  chunkS[2][256];
  __shared__ float  paramsS[2][60];

  {  // stage x[b, k, cp*32+t] -> xH/xL[t][k]; 2 passes, coalesced 16B loads
#pragma unroll
    for (int pass = 0; pass < 2; ++pass) {
      int k = pass * 32 + (tid >> 3), t4 = tid & 7;
      float4 v = *(const float4*)(x + ((size_t)(b * 64 + k)) * 2048 + cp * 32 + t4 * 4);
      float vals[4] = {v.x, v.y, v.z, v.w};
#pragma unroll
      for (int i = 0; i < 4; ++i) {
        __bf16 h = (__bf16)vals[i];
        xH[t4 * 4 + i][k] = h;
        xL[t4 * 4 + i][k] = (__bf16)(vals[i] - (float)h);
      }
    }
  }
  __syncthreads();

  // ---- pipelined GEMM1 -> GEMM2 over 4 d-segments of 64 ----
  f32x4 acc2[2][2];                      // [mt][jt] GEMM2 accumulators (16 regs)
#pragma unroll
  for (int mt = 0; mt < 2; ++mt)
#pragma unroll
    for (int jt = 0; jt < 2; ++jt) acc2[mt][jt] = (f32x4){0.f, 0.f, 0.f, 0.f};

#pragma unroll
  for (int seg = 0; seg < 4; ++seg) {
    const int p = seg & 1;
    {  // GEMM1: this wave computes cols [seg*64 + wv*16, +16) for all 32 rows
      bf16x8 xa[2][2], xl_[2][2];        // [mt][s] from LDS
#pragma unroll
      for (int mt = 0; mt < 2; ++mt)
#pragma unroll
        for (int s = 0; s < 2; ++s) {
          xa[mt][s]  = *(const bf16x8*)&xH[mt * 16 + l15][32 * s + 8 * quad];
          xl_[mt][s] = *(const bf16x8*)&xL[mt * 16 + l15][32 * s + 8 * quad];
        }
      const int dg = seg * 64 + wv * 16 + l15;
      const size_t row = (size_t)dg * 64 + 8 * quad;
      bf16x8 bh0 = *(const bf16x8*)(embH + row);
      bf16x8 bl0 = *(const bf16x8*)(embL + row);
      bf16x8 bh1 = *(const bf16x8*)(embH + row + 32);
      bf16x8 bl1 = *(const bf16x8*)(embL + row + 32);
      float bias = emb_b[dg];
      f32x4 a0 = (f32x4){0.f, 0.f, 0.f, 0.f}, a1 = a0;
      a0 = __builtin_amdgcn_mfma_f32_16x16x32_bf16(xa[0][0], bh0, a0, 0, 0, 0);
      a0 = __builtin_amdgcn_mfma_f32_16x16x32_bf16(xl_[0][0], bh0, a0, 0, 0, 0);
      a0 = __builtin_amdgcn_mfma_f32_16x16x32_bf16(xa[0][0], bl0, a0, 0, 0, 0);
      a0 = __builtin_amdgcn_mfma_f32_16x16x32_bf16(xa[0][1], bh1, a0, 0, 0, 0);
      a0 = __builtin_amdgcn_mfma_f32_16x16x32_bf16(xl_[0][1], bh1, a0, 0, 0, 0);
      a0 = __builtin_amdgcn_mfma_f32_16x16x32_bf16(xa[0][1], bl1, a0, 0, 0, 0);
      a1 = __builtin_amdgcn_mfma_f32_16x16x32_bf16(xa[1][0], bh0, a1, 0, 0, 0);
      a1 = __builtin_amdgcn_mfma_f32_16x16x32_bf16(xl_[1][0], bh0, a1, 0, 0, 0);
      a1 = __builtin_amdgcn_mfma_f32_16x16x32_bf16(xa[1][0], bl0, a1, 0, 0, 0);
      a1 = __builtin_amdgcn_mfma_f32_16x16x32_bf16(xa[1][1], bh1, a1, 0, 0, 0);
      a1 = __builtin_amdgcn_mfma_f32_16x16x32_bf16(xl_[1][1], bh1, a1, 0, 0, 0);
      a1 = __builtin_amdgcn_mfma_f32_16x16x32_bf16(xa[1][1], bl1, a1, 0, 0, 0);
      const int col = wv * 16 + l15;
#pragma unroll
      for (int r = 0; r < 4; ++r) {
        float v0 = a0[r] + bias;
        __bf16 h0 = (__bf16)v0;
        bufH[p][quad * 4 + r][col] = h0;
        bufL[p][quad * 4 + r][col] = (__bf16)(v0 - (float)h0);
        float v1 = a1[r] + bias;
        __bf16 h1 = (__bf16)v1;
        bufH[p][16 + quad * 4 + r][col] = h1;
        bufL[p][16 + quad * 4 + r][col] = (__bf16)(v1 - (float)h1);
      }
    }
    __syncthreads();
    // GEMM2 partial: K-slice [seg*64, +64) as 2 k-steps of 32
#pragma unroll
    for (int ss = 0; ss < 2; ++ss) {
      bf16x8 fa[2], fb[2];
#pragma unroll
      for (int mt = 0; mt < 2; ++mt) {
        fa[mt] = *(const bf16x8*)&bufH[p][mt * 16 + l15][32 * ss + 8 * quad];
        fb[mt] = *(const bf16x8*)&bufL[p][mt * 16 + l15][32 * ss + 8 * quad];
      }
#pragma unroll
      for (int jt = 0; jt < 2; ++jt) {
        const size_t row = (size_t)(wv * 32 + jt * 16 + l15) * 256 + seg * 64 + 32 * ss + 8 * quad;
        bf16x8 bh = *(const bf16x8*)(attH + row);
        bf16x8 bl = *(const bf16x8*)(attL + row);
#pragma unroll
        for (int mt = 0; mt < 2; ++mt) {
          acc2[mt][jt] = __builtin_amdgcn_mfma_f32_16x16x32_bf16(fa[mt], bh, acc2[mt][jt], 0, 0, 0);
          acc2[mt][jt] = __builtin_amdgcn_mfma_f32_16x16x32_bf16(fb[mt], bh, acc2[mt][jt], 0, 0, 0);
          acc2[mt][jt] = __builtin_amdgcn_mfma_f32_16x16x32_bf16(fa[mt], bl, acc2[mt][jt], 0, 0, 0);
        }
      }
    }
    // no 2nd barrier: seg s+2 overwrites buf[p] only after the next seg's
    // barrier, which orders all gemm2(buf[p]) reads before that write.
  }

  {  // scores epilogue: tanh, * w2, reduce over the 16 j's in l15
    float w2v[2], b1v[2];
#pragma unroll
    for (int jt = 0; jt < 2; ++jt) {
      int j = wv * 32 + jt * 16 + l15;
      w2v[jt] = att_w2[j];
      b1v[jt] = att_b1[j];
    }
#pragma unroll
    for (int mt = 0; mt < 2; ++mt)
#pragma unroll
      for (int r = 0; r < 4; ++r) {
        float sc = fast_tanh(acc2[mt][0][r] + b1v[0]) * w2v[0] +
                   fast_tanh(acc2[mt][1][r] + b1v[1]) * w2v[1];
        sc += __shfl_xor(sc, 1, 64);
        sc += __shfl_xor(sc, 2, 64);
        sc += __shfl_xor(sc, 4, 64);
        sc += __shfl_xor(sc, 8, 64);
        if (l15 == 0) scoreS[wv][mt * 16 + quad * 4 + r] = sc;
      }
  }
  __syncthreads();

  if (tid < 2) {  // softmax over 16 per chunk (att_b2 dropped: shift-invariant)
    float s[16], mx = -1e30f;
#pragma unroll
    for (int t = 0; t < 16; ++t) {
      int tt = tid * 16 + t;
      s[t] = (scoreS[0][tt] + scoreS[1][tt]) + (scoreS[2][tt] + scoreS[3][tt]);
      mx = fmaxf(mx, s[t]);
    }
    float sum = 0.f;
#pragma unroll
    for (int t = 0; t < 16; ++t) { s[t] = __expf(s[t] - mx); sum += s[t]; }
    float inv = 1.f / sum;
#pragma unroll
    for (int t = 0; t < 16; ++t) wSm[tid][t] = s[t] * inv;
  }
  __syncthreads();

  if (tid < 128) {  // xagg[c][k] = sum_t w[c,t]*x[c*16+t][k] from LDS (hi+lo)
    const int c = tid >> 6, k = tid & 63;
    float a = 0.f;
#pragma unroll
    for (int t = 0; t < 16; ++t) {
      float xv = (float)xH[c * 16 + t][k] + (float)xL[c * 16 + t][k];
      a = fmaf(wSm[c][t], xv, a);
    }
    xaggS[c][k] = a;
  }
  __syncthreads();

  {  // chunk[c][d] = sum_k xagg[c][k]*emb_w[k][d] + emb_b[d]  (pure fp32)
    const int d = tid;
    float c0 = emb_b[d], c1 = c0;
#pragma unroll 8
    for (int k = 0; k < 64; ++k) {
      float wgt = emb_w[k * 256 + d];
      c0 = fmaf(xaggS[0][k], wgt, c0);
      c1 = fmaf(xaggS[1][k], wgt, c1);
    }
    chunkS[0][d] = c0; chunkS[1][d] = c1;
  }
  __syncthreads();

  {  // proj via MFMA: params[2][60] = sigmoid(chunk @ proj_w + b)
    const int jout = wv * 16 + l15;
    f32x4 acc3 = (f32x4){0.f, 0.f, 0.f, 0.f};
#pragma unroll
    for (int s = 0; s < 8; ++s) {
      const size_t row = (size_t)jout * 256 + 32 * s + 8 * quad;
      bf16x8 bh = *(const bf16x8*)(projTH + row);
      bf16x8 bl = *(const bf16x8*)(projTL + row);
      bf16x8 ax = (bf16x8)(__bf16)0.f, alx = (bf16x8)(__bf16)0.f;
      if (l15 < 2) {
        const float* cs = &chunkS[l15][32 * s + 8 * quad];
        float4 u0 = *(const float4*)cs, u1 = *(const float4*)(cs + 4);
        float vals[8] = {u0.x, u0.y, u0.z, u0.w, u1.x, u1.y, u1.z, u1.w};
#pragma unroll
        for (int j = 0; j < 8; ++j) {
          __bf16 h = (__bf16)vals[j];
          ax[j] = h;
          alx[j] = (__bf16)(vals[j] - (float)h);
        }
      }
      acc3 = __builtin_amdgcn_mfma_f32_16x16x32_bf16(ax, bh, acc3, 0, 0, 0);
      acc3 = __builtin_amdgcn_mfma_f32_16x16x32_bf16(alx, bh, acc3, 0, 0, 0);
      acc3 = __builtin_amdgcn_mfma_f32_16x16x32_bf16(ax, bl, acc3, 0, 0, 0);
    }
    if (jout < 60 && quad == 0) {
      float pbias = proj_b[jout];
#pragma unroll
      for (int r = 0; r < 2; ++r) {
        float a = acc3[r] + pbias;
        paramsS[r][jout] = 1.f / (1.f + __expf(-a));
      }
    }
  }
  __syncthreads();

  // ---- fused K2: waves 0,1 evolve their chunk's statevector ----
  if (wv < 2) {
    float re = (lane == 0) ? 1.f : 0.f, im = 0.f;
    const float* p = paramsS[wv];
    ansatz_layer(re, im, lane, p);
    ansatz_layer(re, im, lane, p + 30);
    evolved[((size_t)b * NCH + cp * 2 + wv) * QDIM + lane] = make_float2(re, im);
  }
}

// ============ K3: LCU mix + qff ansatz + expvals + head (512 thr) ============
__global__ __launch_bounds__(512) void k3_head(
    const float2* __restrict__ evolved, const float* __restrict__ mix_re,
    const float* __restrict__ mix_im, const float* __restrict__ qff,
    const float* __restrict__ out_w, const float* __restrict__ out_b,
    const float* __restrict__ ln_g, const float* __restrict__ ln_b,
    const float* __restrict__ cls_w1, const float* __restrict__ cls_b1,
    const float* __restrict__ cls_w2, const float* __restrict__ cls_b2,
    float* __restrict__ outp) {
  const int b = blockIdx.x, tid = threadIdx.x, wv = tid >> 6, lane = tid & 63;
  __shared__ float mreS[8][64], mimS[8][64];
  __shared__ float qfeatS[18];
  __shared__ float outS[DD];
  __shared__ float redS[8];
  __shared__ float clsR[2][DD];

  float are = 0.f, aim = 0.f;
#pragma unroll 4
  for (int t = wv * 16; t < wv * 16 + 16; ++t) {
    float2 e = evolved[((size_t)b * NCH + t) * QDIM + lane];
    float cr = mix_re[t], ci = mix_im[t];
    are = fmaf(cr, e.x, are); are = fmaf(-ci, e.y, are);
    aim = fmaf(cr, e.y, aim); aim = fmaf(ci, e.x, aim);
  }
  mreS[wv][lane] = are; mimS[wv][lane] = aim;
  __syncthreads();

  if (wv == 0) {
    float r0 = mix_re[lane], i0 = mix_im[lane];
    float r1 = mix_re[lane + 64], i1 = mix_im[lane + 64];
    float sp = sqrtf(r0 * r0 + i0 * i0) + sqrtf(r1 * r1 + i1 * i1);
    float S = wave_sum(sp) + 1e-8f;
    float re = 0.f, im = 0.f;
#pragma unroll
    for (int w = 0; w < 8; ++w) { re += mreS[w][lane]; im += mimS[w][lane]; }
    float invS = 1.f / S;
    re *= invS; im *= invS;
    float n2 = wave_sum(re * re + im * im);
    float scl = 1.f / (sqrtf(n2) + 1e-9f);
    re *= scl; im *= scl;
    float qp[30];
#pragma unroll
    for (int i = 0; i < 30; ++i) qp[i] = qff[i];
    ansatz_layer(re, im, lane, qp);
#pragma unroll
    for (int q = 0; q < 6; ++q) {
      int m = 1 << (5 - q);
      float pre = __shfl_xor(re, m, 64), pim = __shfl_xor(im, m, 64);
      float vx = re * pre + im * pim;
      float vy = (lane & m) ? (im * pre - re * pim) : (re * pim - im * pre);
      float vz = (lane & m) ? -(re * re + im * im) : (re * re + im * im);
      vx = wave_sum(vx); vy = wave_sum(vy); vz = wave_sum(vz);
      if (lane == 0) { qfeatS[q] = vx; qfeatS[6 + q] = vy; qfeatS[12 + q] = vz; }
    }
  }
  __syncthreads();

  float o = 0.f, dv = 0.f;
  if (tid < 256) {
    o = out_b[tid];
#pragma unroll
    for (int k = 0; k < 18; ++k) o = fmaf(qfeatS[k], out_w[k * DD + tid], o);
    float s1 = wave_sum(o);
    if (lane == 0) redS[wv] = s1;
  }
  __syncthreads();
  float mu = (redS[0] + redS[1] + redS[2] + redS[3]) * (1.f / 256.f);
  if (tid < 256) {
    dv = o - mu;
    float s2 = wave_sum(dv * dv);
    if (lane == 0) redS[wv] = s2;
  }
  __syncthreads();
  float var = (redS[0] + redS[1] + redS[2] + redS[3]) * (1.f / 256.f);
  if (tid < 256) {
    outS[tid] = dv / sqrtf(var + 1e-5f) * ln_g[tid] + ln_b[tid];
  }
  __syncthreads();

  {
    const int dd = tid & 255, hh = tid >> 8;
    float r = (hh == 0) ? cls_b1[dd] : 0.f;
#pragma unroll 8
    for (int d = hh * 128; d < hh * 128 + 128; ++d)
      r = fmaf(outS[d], cls_w1[(size_t)d * DD + dd], r);
    clsR[hh][dd] = r;
  }
  __syncthreads();
  if (tid < 256) {
    float r = fmaxf(clsR[0][tid] + clsR[1][tid], 0.f);
    float p0 = wave_sum(r * cls_w2[tid * 2 + 0]);
    float p1 = wave_sum(r * cls_w2[tid * 2 + 1]);
    if (lane == 0) { mreS[0][wv] = p0; mreS[1][wv] = p1; }
  }
  __syncthreads();
  if (tid == 0) {
    outp[b * 2 + 0] = (mreS[0][0] + mreS[0][1]) + (mreS[0][2] + mreS[0][3]) + cls_b2[0];
    outp[b * 2 + 1] = (mreS[1][0] + mreS[1][1]) + (mreS[1][2] + mreS[1][3]) + cls_b2[1];
  }
}

extern "C" void kernel_launch(void* const* d_in, const int* in_sizes, int n_in,
                              void* d_out, int out_size, void* d_ws, size_t ws_size,
                              hipStream_t stream) {
  const float* x      = (const float*)d_in[0];
  const float* emb_w  = (const float*)d_in[1];
  const float* emb_b  = (const float*)d_in[2];
  const float* att_w1 = (const float*)d_in[3];
  const float* att_b1 = (const float*)d_in[4];
  const float* att_w2 = (const float*)d_in[5];
  // d_in[6] att_b2: unused (softmax shift-invariant)
  const float* proj_w = (const float*)d_in[7];
  const float* proj_b = (const float*)d_in[8];
  const float* mix_re = (const float*)d_in[9];
  const float* mix_im = (const float*)d_in[10];
  const float* qff    = (const float*)d_in[11];
  const float* out_w  = (const float*)d_in[12];
  const float* out_b  = (const float*)d_in[13];
  const float* ln_g   = (const float*)d_in[14];
  const float* ln_b   = (const float*)d_in[15];
  const float* cls_w1 = (const float*)d_in[16];
  const float* cls_b1 = (const float*)d_in[17];
  const float* cls_w2 = (const float*)d_in[18];
  const float* cls_b2 = (const float*)d_in[19];

  char* ws = (char*)d_ws;
  float2* evolved = (float2*)ws;                     // 16384*64*8 = 8,388,608
  size_t off = 8388608;
  __bf16* embH   = (__bf16*)(ws + off); off += 32768;
  __bf16* embL   = (__bf16*)(ws + off); off += 32768;
  __bf16* attH   = (__bf16*)(ws + off); off += 65536;
  __bf16* attL   = (__bf16*)(ws + off); off += 65536;
  __bf16* projTH = (__bf16*)(ws + off); off += 32768;
  __bf16* projTL = (__bf16*)(ws + off); off += 32768;

  k0_prep<<<256, 256, 0, stream>>>(emb_w, att_w1, proj_w,
                                   embH, embL, attH, attL, projTH, projTL);
  k1_fused<<<BB * 64, 256, 0, stream>>>(
      x, emb_w, emb_b, att_b1, att_w2, proj_b,
      embH, embL, attH, attL, projTH, projTL, evolved);
  k3_head<<<BB, 512, 0, stream>>>(evolved, mix_re, mix_im, qff, out_w, out_b,
                                  ln_g, ln_b, cls_w1, cls_b1, cls_w2, cls_b2,
                                  (float*)d_out);
}

// Round 8
// 214.575 us; speedup vs baseline: 2.0360x; 1.8297x over previous
//
#include <hip/hip_runtime.h>
#include <math.h>

#define NQ    6
#define QDIM  64
#define BB    128
#define CC    64
#define TT    2048
#define DD    256
#define NCH   128
#define CHLEN 16
#define HH    128
#define NCP   60

typedef __bf16 bf16x8 __attribute__((ext_vector_type(8)));
typedef float  f32x4  __attribute__((ext_vector_type(4)));

__device__ __forceinline__ float fast_tanh(float x) {
  float e = __expf(2.f * x);
  return 1.f - 2.f / (e + 1.f);
}

__device__ __forceinline__ float wave_sum(float v) {
#pragma unroll
  for (int off = 32; off >= 1; off >>= 1) v += __shfl_xor(v, off, 64);
  return v;
}

// ---- quantum gates: one statevector per wave, (re,im) per lane ----
__device__ __forceinline__ void g_rx(float& re, float& im, int lane, int m, float half) {
  float c = __cosf(half), s = __sinf(half);
  float pre = __shfl_xor(re, m, 64);
  float pim = __shfl_xor(im, m, 64);
  float nre = c * re + s * pim;
  float nim = c * im - s * pre;
  re = nre; im = nim;
}
__device__ __forceinline__ void g_ry(float& re, float& im, int lane, int m, float half) {
  float c = __cosf(half), s = __sinf(half);
  float pre = __shfl_xor(re, m, 64);
  float pim = __shfl_xor(im, m, 64);
  float sg = (lane & m) ? s : -s;
  re = c * re + sg * pre;
  im = c * im + sg * pim;
}
__device__ __forceinline__ void g_rz(float& re, float& im, int lane, int m, float half) {
  float c = __cosf(half), s = __sinf(half);
  float sg = (lane & m) ? s : -s;
  float nre = c * re - sg * im;
  float nim = c * im + sg * re;
  re = nre; im = nim;
}
__device__ __forceinline__ void g_crx(float& re, float& im, int lane, int mc, int mt, float half) {
  float c = __cosf(half), s = __sinf(half);
  float pre = __shfl_xor(re, mt, 64);
  float pim = __shfl_xor(im, mt, 64);
  if (lane & mc) {
    float nre = c * re + s * pim;
    float nim = c * im - s * pre;
    re = nre; im = nim;
  }
}
__device__ __forceinline__ void ansatz_layer(float& re, float& im, int lane,
                                             const float* p) {
#pragma unroll
  for (int q = 0; q < 6; ++q) {
    int m = 1 << (5 - q);
    g_rx(re, im, lane, m, 0.5f * p[3 * q + 0]);
    g_ry(re, im, lane, m, 0.5f * p[3 * q + 1]);
    g_rz(re, im, lane, m, 0.5f * p[3 * q + 2]);
  }
#pragma unroll
  for (int q = 0; q < 6; ++q)
    g_crx(re, im, lane, 1 << (5 - q), 1 << (5 - ((q + 1) % 6)), 0.5f * p[18 + q]);
#pragma unroll
  for (int q = 5; q >= 0; --q)
    g_crx(re, im, lane, 1 << (5 - q), 1 << (5 - ((q + 5) % 6)), 0.5f * p[24 + (5 - q)]);
}

// ============ K0: fused-weight prep (fp32 contractions, then split-bf16) ====
// W_fusedT[j][k] = sum_d emb_w[k,d]*att_w1[d,j]         (128 x 64)
// P_fusedT[n][k] = sum_d emb_w[k,d]*proj_w[d,n] (n<60)  (64 x 64, rows>=60 = 0)
// b_fused[j]  = sum_d emb_b[d]*att_w1[d,j] + att_b1[j]
// pb_fused[n] = sum_d emb_b[d]*proj_w[d,n] + proj_b[n]
__global__ __launch_bounds__(256) void k0_prep(
    const float* __restrict__ emb_w, const float* __restrict__ emb_b,
    const float* __restrict__ att_w1, const float* __restrict__ att_b1,
    const float* __restrict__ proj_w, const float* __restrict__ proj_b,
    __bf16* __restrict__ WfH, __bf16* __restrict__ WfL,
    __bf16* __restrict__ PfH, __bf16* __restrict__ PfL,
    float* __restrict__ b_fused, float* __restrict__ pb_fused) {
  int idx = blockIdx.x * 256 + threadIdx.x;
  if (idx < 8192) {                         // W_fusedT
    int j = idx & 127, k = idx >> 7;
    float a = 0.f;
    for (int d = 0; d < 256; ++d)
      a = fmaf(emb_w[k * 256 + d], att_w1[d * 128 + j], a);
    __bf16 h = (__bf16)a;
    WfH[j * 64 + k] = h; WfL[j * 64 + k] = (__bf16)(a - (float)h);
  } else if (idx < 12288) {                 // P_fusedT
    int i = idx - 8192;
    int n = i & 63, k = i >> 6;
    float a = 0.f;
    if (n < 60)
      for (int d = 0; d < 256; ++d)
        a = fmaf(emb_w[k * 256 + d], proj_w[d * 60 + n], a);
    __bf16 h = (__bf16)a;
    PfH[n * 64 + k] = h; PfL[n * 64 + k] = (__bf16)(a - (float)h);
  } else if (idx < 12416) {                 // b_fused
    int j = idx - 12288;
    float a = att_b1[j];
    for (int d = 0; d < 256; ++d) a = fmaf(emb_b[d], att_w1[d * 128 + j], a);
    b_fused[j] = a;
  } else if (idx < 12480) {                 // pb_fused
    int n = idx - 12416;
    float a = 0.f;
    if (n < 60) {
      a = proj_b[n];
      for (int d = 0; d < 256; ++d) a = fmaf(emb_b[d], proj_w[d * 60 + n], a);
    }
    pb_fused[n] = a;
  }
}

// ============ K1: fused h-GEMM + softmax + xagg + params + ansatz ============
// Split-bf16 3-product MFMA. m89 layouts: A[m=lane&15][k=quad*8+j],
// B[n=lane&15][k=quad*8+j], C: n=lane&15, m=quad*4+reg.
// tanh is the only nonlinearity between x and scores, so
// h = tanh(x^T @ W_fused + b_fused) with K=64 (GEMM2's K=256 fused away in k0);
// params = sigmoid(xagg @ P_fused + pb_fused) via the bilinear chunk identity.
// x staged fp32 in LDS (A-frags + exact xagg); nothing big in regs across
// barriers (R6 lesson). LDS ~10.4 KB -> 8 blocks/CU (wave-capped).
__global__ __launch_bounds__(256) void k1_fused(
    const float* __restrict__ x, const float* __restrict__ att_w2,
    const __bf16* __restrict__ WfH, const __bf16* __restrict__ WfL,
    const __bf16* __restrict__ PfH, const __bf16* __restrict__ PfL,
    const float* __restrict__ b_fused, const float* __restrict__ pb_fused,
    float2* __restrict__ evolved) {
  const int blk = blockIdx.x;            // 8192 = 128 b x 64 chunk-pairs
  const int b = blk >> 6, cp = blk & 63;
  const int tid = threadIdx.x, wv = tid >> 6, lane = tid & 63;
  const int l15 = lane & 15, quad = lane >> 4;

  __shared__ float xtile[32][68];        // x^T [t][k] fp32 (word-stride 68)
  __shared__ float scoreS[4][32];
  __shared__ float wSm[2][16];
  __shared__ float xaggS[2][64];
  __shared__ float paramsS[2][60];

  {  // stage x[b, k, cp*32+t] -> xtile[t][k]; 2 passes, coalesced 16B loads
#pragma unroll
    for (int pass = 0; pass < 2; ++pass) {
      int k = pass * 32 + (tid >> 3), t4 = tid & 7;
      float4 v = *(const float4*)(x + ((size_t)(b * 64 + k)) * 2048 + cp * 32 + t4 * 4);
      xtile[t4 * 4 + 0][k] = v.x; xtile[t4 * 4 + 1][k] = v.y;
      xtile[t4 * 4 + 2][k] = v.z; xtile[t4 * 4 + 3][k] = v.w;
    }
  }
  __syncthreads();

  // ---- GEMM_h: h_pre[32][128] = x^T @ W_fused; wave owns j = wv*32..+31 ----
  f32x4 acc[2][2];                       // [mt][jt]
#pragma unroll
  for (int mt = 0; mt < 2; ++mt)
#pragma unroll
    for (int jt = 0; jt < 2; ++jt) acc[mt][jt] = (f32x4){0.f, 0.f, 0.f, 0.f};
#pragma unroll
  for (int mt = 0; mt < 2; ++mt) {       // mt-sectioned to bound VGPR liveness
    bf16x8 ah[2], al[2];                 // [ks]
#pragma unroll
    for (int ks = 0; ks < 2; ++ks) {
      const float* src = &xtile[mt * 16 + l15][ks * 32 + 8 * quad];
      float4 u0 = *(const float4*)src, u1 = *(const float4*)(src + 4);
      float vals[8] = {u0.x, u0.y, u0.z, u0.w, u1.x, u1.y, u1.z, u1.w};
#pragma unroll
      for (int j = 0; j < 8; ++j) {
        __bf16 h = (__bf16)vals[j];
        ah[ks][j] = h;
        al[ks][j] = (__bf16)(vals[j] - (float)h);
      }
    }
#pragma unroll
    for (int jt = 0; jt < 2; ++jt)
#pragma unroll
      for (int ks = 0; ks < 2; ++ks) {
        const size_t row = (size_t)(wv * 32 + jt * 16 + l15) * 64 + ks * 32 + 8 * quad;
        bf16x8 bh = *(const bf16x8*)(WfH + row);
        bf16x8 bl = *(const bf16x8*)(WfL + row);
        acc[mt][jt] = __builtin_amdgcn_mfma_f32_16x16x32_bf16(ah[ks], bh, acc[mt][jt], 0, 0, 0);
        acc[mt][jt] = __builtin_amdgcn_mfma_f32_16x16x32_bf16(al[ks], bh, acc[mt][jt], 0, 0, 0);
        acc[mt][jt] = __builtin_amdgcn_mfma_f32_16x16x32_bf16(ah[ks], bl, acc[mt][jt], 0, 0, 0);
      }
  }
  {  // scores epilogue: tanh, * w2, reduce over the 16 j's in l15
    float w2v[2], b1v[2];
#pragma unroll
    for (int jt = 0; jt < 2; ++jt) {
      int j = wv * 32 + jt * 16 + l15;
      w2v[jt] = att_w2[j];
      b1v[jt] = b_fused[j];
    }
#pragma unroll
    for (int mt = 0; mt < 2; ++mt)
#pragma unroll
      for (int r = 0; r < 4; ++r) {
        float sc = fast_tanh(acc[mt][0][r] + b1v[0]) * w2v[0] +
                   fast_tanh(acc[mt][1][r] + b1v[1]) * w2v[1];
        sc += __shfl_xor(sc, 1, 64);
        sc += __shfl_xor(sc, 2, 64);
        sc += __shfl_xor(sc, 4, 64);
        sc += __shfl_xor(sc, 8, 64);
        if (l15 == 0) scoreS[wv][mt * 16 + quad * 4 + r] = sc;
      }
  }
  __syncthreads();

  if (tid < 2) {  // softmax over 16 per chunk (att_b2 dropped: shift-invariant)
    float s[16], mx = -1e30f;
#pragma unroll
    for (int t = 0; t < 16; ++t) {
      int tt = tid * 16 + t;
      s[t] = (scoreS[0][tt] + scoreS[1][tt]) + (scoreS[2][tt] + scoreS[3][tt]);
      mx = fmaxf(mx, s[t]);
    }
    float sum = 0.f;
#pragma unroll
    for (int t = 0; t < 16; ++t) { s[t] = __expf(s[t] - mx); sum += s[t]; }
    float inv = 1.f / sum;
#pragma unroll
    for (int t = 0; t < 16; ++t) wSm[tid][t] = s[t] * inv;
  }
  __syncthreads();

  if (tid < 128) {  // xagg[c][k] = sum_t w[c,t]*x[c*16+t][k] (fp32, exact)
    const int c = tid >> 6, k = tid & 63;
    float a = 0.f;
#pragma unroll
    for (int t = 0; t < 16; ++t) a = fmaf(wSm[c][t], xtile[c * 16 + t][k], a);
    xaggS[c][k] = a;
  }
  __syncthreads();

  {  // params[2][60] = sigmoid(xagg @ P_fused + pb_fused); 1 n-tile per wave
    const int jout = wv * 16 + l15;
    f32x4 acc3 = (f32x4){0.f, 0.f, 0.f, 0.f};
#pragma unroll
    for (int ks = 0; ks < 2; ++ks) {
      const size_t row = (size_t)jout * 64 + ks * 32 + 8 * quad;
      bf16x8 bh = *(const bf16x8*)(PfH + row);
      bf16x8 bl = *(const bf16x8*)(PfL + row);
      bf16x8 ax = (bf16x8)(__bf16)0.f, alx = (bf16x8)(__bf16)0.f;
      if (l15 < 2) {
        const float* cs = &xaggS[l15][ks * 32 + 8 * quad];
        float4 u0 = *(const float4*)cs, u1 = *(const float4*)(cs + 4);
        float vals[8] = {u0.x, u0.y, u0.z, u0.w, u1.x, u1.y, u1.z, u1.w};
#pragma unroll
        for (int j = 0; j < 8; ++j) {
          __bf16 h = (__bf16)vals[j];
          ax[j] = h;
          alx[j] = (__bf16)(vals[j] - (float)h);
        }
      }
      acc3 = __builtin_amdgcn_mfma_f32_16x16x32_bf16(ax, bh, acc3, 0, 0, 0);
      acc3 = __builtin_amdgcn_mfma_f32_16x16x32_bf16(alx, bh, acc3, 0, 0, 0);
      acc3 = __builtin_amdgcn_mfma_f32_16x16x32_bf16(ax, bl, acc3, 0, 0, 0);
    }
    if (jout < 60 && quad == 0) {
      float pbias = pb_fused[jout];
#pragma unroll
      for (int r = 0; r < 2; ++r) {
        float a = acc3[r] + pbias;
        paramsS[r][jout] = 1.f / (1.f + __expf(-a));
      }
    }
  }
  __syncthreads();

  // ---- fused K2: waves 0,1 evolve their chunk's statevector ----
  if (wv < 2) {
    float re = (lane == 0) ? 1.f : 0.f, im = 0.f;
    const float* p = paramsS[wv];
    ansatz_layer(re, im, lane, p);
    ansatz_layer(re, im, lane, p + 30);
    evolved[((size_t)b * NCH + cp * 2 + wv) * QDIM + lane] = make_float2(re, im);
  }
}

// ============ K3: LCU mix + qff ansatz + expvals + head (512 thr) ============
__global__ __launch_bounds__(512) void k3_head(
    const float2* __restrict__ evolved, const float* __restrict__ mix_re,
    const float* __restrict__ mix_im, const float* __restrict__ qff,
    const float* __restrict__ out_w, const float* __restrict__ out_b,
    const float* __restrict__ ln_g, const float* __restrict__ ln_b,
    const float* __restrict__ cls_w1, const float* __restrict__ cls_b1,
    const float* __restrict__ cls_w2, const float* __restrict__ cls_b2,
    float* __restrict__ outp) {
  const int b = blockIdx.x, tid = threadIdx.x, wv = tid >> 6, lane = tid & 63;
  __shared__ float mreS[8][64], mimS[8][64];
  __shared__ float qfeatS[18];
  __shared__ float outS[DD];
  __shared__ float redS[8];
  __shared__ float clsR[2][DD];

  float are = 0.f, aim = 0.f;
#pragma unroll 4
  for (int t = wv * 16; t < wv * 16 + 16; ++t) {
    float2 e = evolved[((size_t)b * NCH + t) * QDIM + lane];
    float cr = mix_re[t], ci = mix_im[t];
    are = fmaf(cr, e.x, are); are = fmaf(-ci, e.y, are);
    aim = fmaf(cr, e.y, aim); aim = fmaf(ci, e.x, aim);
  }
  mreS[wv][lane] = are; mimS[wv][lane] = aim;
  __syncthreads();

  if (wv == 0) {
    float r0 = mix_re[lane], i0 = mix_im[lane];
    float r1 = mix_re[lane + 64], i1 = mix_im[lane + 64];
    float sp = sqrtf(r0 * r0 + i0 * i0) + sqrtf(r1 * r1 + i1 * i1);
    float S = wave_sum(sp) + 1e-8f;
    float re = 0.f, im = 0.f;
#pragma unroll
    for (int w = 0; w < 8; ++w) { re += mreS[w][lane]; im += mimS[w][lane]; }
    float invS = 1.f / S;
    re *= invS; im *= invS;
    float n2 = wave_sum(re * re + im * im);
    float scl = 1.f / (sqrtf(n2) + 1e-9f);
    re *= scl; im *= scl;
    float qp[30];
#pragma unroll
    for (int i = 0; i < 30; ++i) qp[i] = qff[i];
    ansatz_layer(re, im, lane, qp);
#pragma unroll
    for (int q = 0; q < 6; ++q) {
      int m = 1 << (5 - q);
      float pre = __shfl_xor(re, m, 64), pim = __shfl_xor(im, m, 64);
      float vx = re * pre + im * pim;
      float vy = (lane & m) ? (im * pre - re * pim) : (re * pim - im * pre);
      float vz = (lane & m) ? -(re * re + im * im) : (re * re + im * im);
      vx = wave_sum(vx); vy = wave_sum(vy); vz = wave_sum(vz);
      if (lane == 0) { qfeatS[q] = vx; qfeatS[6 + q] = vy; qfeatS[12 + q] = vz; }
    }
  }
  __syncthreads();

  float o = 0.f, dv = 0.f;
  if (tid < 256) {
    o = out_b[tid];
#pragma unroll
    for (int k = 0; k < 18; ++k) o = fmaf(qfeatS[k], out_w[k * DD + tid], o);
    float s1 = wave_sum(o);
    if (lane == 0) redS[wv] = s1;
  }
  __syncthreads();
  float mu = (redS[0] + redS[1] + redS[2] + redS[3]) * (1.f / 256.f);
  if (tid < 256) {
    dv = o - mu;
    float s2 = wave_sum(dv * dv);
    if (lane == 0) redS[wv] = s2;
  }
  __syncthreads();
  float var = (redS[0] + redS[1] + redS[2] + redS[3]) * (1.f / 256.f);
  if (tid < 256) {
    outS[tid] = dv / sqrtf(var + 1e-5f) * ln_g[tid] + ln_b[tid];
  }
  __syncthreads();

  {
    const int dd = tid & 255, hh = tid >> 8;
    float r = (hh == 0) ? cls_b1[dd] : 0.f;
#pragma unroll 8
    for (int d = hh * 128; d < hh * 128 + 128; ++d)
      r = fmaf(outS[d], cls_w1[(size_t)d * DD + dd], r);
    clsR[hh][dd] = r;
  }
  __syncthreads();
  if (tid < 256) {
    float r = fmaxf(clsR[0][tid] + clsR[1][tid], 0.f);
    float p0 = wave_sum(r * cls_w2[tid * 2 + 0]);
    float p1 = wave_sum(r * cls_w2[tid * 2 + 1]);
    if (lane == 0) { mreS[0][wv] = p0; mreS[1][wv] = p1; }
  }
  __syncthreads();
  if (tid == 0) {
    outp[b * 2 + 0] = (mreS[0][0] + mreS[0][1]) + (mreS[0][2] + mreS[0][3]) + cls_b2[0];
    outp[b * 2 + 1] = (mreS[1][0] + mreS[1][1]) + (mreS[1][2] + mreS[1][3]) + cls_b2[1];
  }
}

extern "C" void kernel_launch(void* const* d_in, const int* in_sizes, int n_in,
                              void* d_out, int out_size, void* d_ws, size_t ws_size,
                              hipStream_t stream) {
  const float* x      = (const float*)d_in[0];
  const float* emb_w  = (const float*)d_in[1];
  const float* emb_b  = (const float*)d_in[2];
  const float* att_w1 = (const float*)d_in[3];
  const float* att_b1 = (const float*)d_in[4];
  const float* att_w2 = (const float*)d_in[5];
  // d_in[6] att_b2: unused (softmax shift-invariant)
  const float* proj_w = (const float*)d_in[7];
  const float* proj_b = (const float*)d_in[8];
  const float* mix_re = (const float*)d_in[9];
  const float* mix_im = (const float*)d_in[10];
  const float* qff    = (const float*)d_in[11];
  const float* out_w  = (const float*)d_in[12];
  const float* out_b  = (const float*)d_in[13];
  const float* ln_g   = (const float*)d_in[14];
  const float* ln_b   = (const float*)d_in[15];
  const float* cls_w1 = (const float*)d_in[16];
  const float* cls_b1 = (const float*)d_in[17];
  const float* cls_w2 = (const float*)d_in[18];
  const float* cls_b2 = (const float*)d_in[19];

  char* ws = (char*)d_ws;
  float2* evolved = (float2*)ws;                     // 16384*64*8 = 8,388,608
  size_t off = 8388608;
  __bf16* WfH = (__bf16*)(ws + off); off += 16384;   // 128x64 bf16
  __bf16* WfL = (__bf16*)(ws + off); off += 16384;
  __bf16* PfH = (__bf16*)(ws + off); off += 8192;    // 64x64 bf16
  __bf16* PfL = (__bf16*)(ws + off); off += 8192;
  float* b_fused  = (float*)(ws + off); off += 512;
  float* pb_fused = (float*)(ws + off); off += 256;

  k0_prep<<<49, 256, 0, stream>>>(emb_w, emb_b, att_w1, att_b1, proj_w, proj_b,
                                  WfH, WfL, PfH, PfL, b_fused, pb_fused);
  k1_fused<<<BB * 64, 256, 0, stream>>>(
      x, att_w2, WfH, WfL, PfH, PfL, b_fused, pb_fused, evolved);
  k3_head<<<BB, 512, 0, stream>>>(evolved, mix_re, mix_im, qff, out_w, out_b,
                                  ln_g, ln_b, cls_w1, cls_b1, cls_w2, cls_b2,
                                  (float*)d_out);
}